// Round 9
// baseline (114.825 us; speedup 1.0000x reference)
//
#include <hip/hip_runtime.h>

// Problem constants
#define BB 32
#define SS 512
#define DD 768
#define HH 12
#define HDIM 64
#define OL 256        // pooled query length
#define NQKV 2304     // 3*DD
#define GM (BB*SS)    // 16384 rows into the QKV GEMM

#define NEG2 (-14426.9504089f)   // -10000 * log2(e)

typedef __bf16 bf16_t;
typedef bf16_t bf16x8 __attribute__((ext_vector_type(8)));
typedef float f32x4 __attribute__((ext_vector_type(4)));
typedef unsigned short u16x8 __attribute__((ext_vector_type(8)));

__device__ __forceinline__ unsigned short f2bf(float f) {
  unsigned u = __float_as_uint(f);
  u = u + 0x7FFFu + ((u >> 16) & 1u);   // RNE
  return (unsigned short)(u >> 16);
}
__device__ __forceinline__ float b2f(unsigned short s) {
  return __uint_as_float(((unsigned)s) << 16);
}

// ---------------------------------------------------------------- conversions
__global__ void conv_f32_bf16(const float* __restrict__ in,
                              unsigned short* __restrict__ out, int n4) {
  int i = blockIdx.x * blockDim.x + threadIdx.x;
  if (i >= n4) return;
  float4 v = ((const float4*)in)[i];
  ushort4 o;
  o.x = f2bf(v.x); o.y = f2bf(v.y); o.z = f2bf(v.z); o.w = f2bf(v.w);
  ((ushort4*)out)[i] = o;
}

// ---------------------------------------------------------------- mask prep
// kbias pre-scaled by log2(e): 0 valid, -14427 masked.
__global__ void prep_mask(const void* __restrict__ mraw,
                          float* __restrict__ kbias,
                          float* __restrict__ invn,
                          unsigned char* __restrict__ nmask,
                          float* __restrict__ out_nm) {
  int b = blockIdx.x, t = threadIdx.x;
  const unsigned char* mb = (const unsigned char*)mraw;
  bool isbyte = (mb[1] != 0);
  int idx = b * SS + t;
  int mv = isbyte ? (int)(mb[idx] != 0) : (int)(((const int*)mraw)[idx] != 0);
  kbias[idx] = mv ? 0.f : NEG2;
  if (t < OL) {
    int i0 = b * SS + 2 * t, i1 = i0 + 1;
    int m0 = isbyte ? (int)(mb[i0] != 0) : (int)(((const int*)mraw)[i0] != 0);
    int m1 = isbyte ? (int)(mb[i1] != 0) : (int)(((const int*)mraw)[i1] != 0);
    int n = m0 + m1;
    invn[b * OL + t] = (n > 0) ? 1.f / (float)n : 1.f;
    nmask[b * OL + t] = (n > 0) ? 1 : 0;
    out_nm[b * OL + t] = (n > 0) ? 1.f : 0.f;   // second tuple output
  }
}

// ---------------------------------------------------------------- QKV GEMM
// 128x256 tile, BK=64, 8 waves (2M x 4N, per-wave 64x64), RING-3 LDS
// (3 x 48 KiB), 4-phase/2-K-tile pipeline, steady vmcnt(6) (never drains),
// T2 XOR-swizzle, T5 setprio, T1 XCD swizzle. 12 K-tiles = 6 iterations.
// Fused epilogues: n-tiles 0-2 -> pooled qp; 3-5 -> Kbuf; 6-8 -> vT.
__global__ __launch_bounds__(512, 2) void gemm_qkv(
    const unsigned short* __restrict__ A,
    const unsigned short* __restrict__ Bt,
    const float* __restrict__ bias,
    unsigned short* __restrict__ Kbuf,   // [B*S][768]
    unsigned short* __restrict__ qp,     // [B*OL][768]
    unsigned short* __restrict__ vT,     // [B][H][64][512]
    const float* __restrict__ kbias,
    const float* __restrict__ invn) {
  __shared__ __align__(16) char smem[147456];   // 3 slots x (A 16K + B 32K)

  const int t = threadIdx.x;
  const int lane = t & 63;
  const int w = t >> 6;          // 0..7
  const int wm = w >> 2;         // 0..1
  const int wn = w & 3;          // 0..3
  const int fr = lane & 15, hi = lane >> 4;

  // T1: 1152 blocks = 8 XCDs x 144 (n fastest: A panel L2-resident per XCD)
  const int p = blockIdx.x;
  const int l = (p & 7) * 144 + (p >> 3);
  const int m0 = (l / 9) * 128;
  const int n0 = (l % 9) * 256;
  const int b = m0 >> 9;
  const int s0 = m0 & 511;

  f32x4 acc[4][4] = {};

  const int sr8 = lane >> 3;
  const int sx8 = ((lane & 7) ^ sr8) * 8;       // pre-swizzled source col
  const int wq = __builtin_amdgcn_readfirstlane(w);
  const unsigned short* aS = A + (size_t)(m0 + wq * 16 + sr8) * DD + sx8;
  const unsigned short* bS = Bt + (size_t)(n0 + wq * 32 + sr8) * DD + sx8;

#define GLOAD(SRC, DST)                                                        \
  __builtin_amdgcn_global_load_lds(                                           \
      (const __attribute__((address_space(1))) unsigned int*)(SRC),           \
      (__attribute__((address_space(3))) unsigned int*)(DST), 16, 0, 0)

  // per K-tile staging: A = 2 issues/thread, B = 4 issues/thread
#define STG_A(KT, SB, Q) GLOAD(aS + (size_t)(8 * (Q)) * DD + (KT) * 64,        \
                               (SB) + (wq * 16 + 8 * (Q)) * 128)
#define STG_B(KT, SB, Q) GLOAD(bS + (size_t)(8 * (Q)) * DD + (KT) * 64,        \
                               (SB) + 16384 + (wq * 32 + 8 * (Q)) * 128)
#define STG_H1(KT, SB) do { STG_A(KT, SB, 0); STG_A(KT, SB, 1); STG_B(KT, SB, 0); } while (0)
#define STG_H2(KT, SB) do { STG_B(KT, SB, 1); STG_B(KT, SB, 2); STG_B(KT, SB, 3); } while (0)

#define SBAR()                                                                 \
  do {                                                                         \
    __builtin_amdgcn_sched_barrier(0);                                         \
    __builtin_amdgcn_s_barrier();                                              \
    __builtin_amdgcn_sched_barrier(0);                                         \
  } while (0)

#define MFMA16(AF, BF)                                                         \
  do {                                                                         \
    asm volatile("s_waitcnt lgkmcnt(0)" ::: "memory");                          \
    __builtin_amdgcn_sched_barrier(0);                                         \
    __builtin_amdgcn_s_setprio(1);                                             \
    _Pragma("unroll")                                                          \
    for (int mf_ = 0; mf_ < 4; ++mf_)                                          \
      _Pragma("unroll")                                                        \
      for (int nf_ = 0; nf_ < 4; ++nf_)                                        \
        acc[mf_][nf_] = __builtin_amdgcn_mfma_f32_16x16x32_bf16(               \
            (AF)[mf_], (BF)[nf_], acc[mf_][nf_], 0, 0, 0);                     \
    __builtin_amdgcn_s_setprio(0);                                             \
  } while (0)

  const int cb0 = (hi * 16) ^ ((fr & 7) << 4);
  const int cb1 = (64 + hi * 16) ^ ((fr & 7) << 4);
  const int arow = (wm * 64 + fr) * 128;          // + mf*2048
  const int brow = 16384 + (wn * 64 + fr) * 128;  // + nf*2048

  // prologue: tiles 0 -> slot0, 1 -> slot1 (12 loads/thread outstanding)
  STG_H1(0, smem); STG_H2(0, smem);
  STG_H1(1, smem + 49152); STG_H2(1, smem + 49152);

  int se = 0;
#pragma unroll
  for (int it = 0; it < 6; ++it) {
    char* sE = smem + se * 49152;
    char* sO = smem + (se == 2 ? 0 : se + 1) * 49152;
    char* dE = smem + (se == 0 ? 2 : se - 1) * 49152;
    char* dO = sE;
    const int ke = 2 * it + 2, ko = 2 * it + 3;

    bf16x8 af[4], bf[4];

    // ---- ph1: even K-tile, ks=0
    asm volatile("s_waitcnt vmcnt(6)" ::: "memory");
    SBAR();
#pragma unroll
    for (int f = 0; f < 4; ++f) af[f] = *(const bf16x8*)(sE + arow + f * 2048 + cb0);
#pragma unroll
    for (int f = 0; f < 4; ++f) bf[f] = *(const bf16x8*)(sE + brow + f * 2048 + cb0);
    if (it < 5) STG_H1(ke, dE);
    MFMA16(af, bf);

    // ---- ph2: even K-tile, ks=1
    SBAR();
#pragma unroll
    for (int f = 0; f < 4; ++f) af[f] = *(const bf16x8*)(sE + arow + f * 2048 + cb1);
#pragma unroll
    for (int f = 0; f < 4; ++f) bf[f] = *(const bf16x8*)(sE + brow + f * 2048 + cb1);
    if (it < 5) STG_H2(ke, dE);
    MFMA16(af, bf);

    // ---- ph3: odd K-tile, ks=0
    if (it < 5) {
      asm volatile("s_waitcnt vmcnt(6)" ::: "memory");
    } else {
      asm volatile("s_waitcnt vmcnt(0)" ::: "memory");
    }
    SBAR();
#pragma unroll
    for (int f = 0; f < 4; ++f) af[f] = *(const bf16x8*)(sO + arow + f * 2048 + cb0);
#pragma unroll
    for (int f = 0; f < 4; ++f) bf[f] = *(const bf16x8*)(sO + brow + f * 2048 + cb0);
    if (it < 5) STG_H1(ko, dO);
    MFMA16(af, bf);

    // ---- ph4: odd K-tile, ks=1
    SBAR();
#pragma unroll
    for (int f = 0; f < 4; ++f) af[f] = *(const bf16x8*)(sO + arow + f * 2048 + cb1);
#pragma unroll
    for (int f = 0; f < 4; ++f) bf[f] = *(const bf16x8*)(sO + brow + f * 2048 + cb1);
    if (it < 5) STG_H2(ko, dO);
    MFMA16(af, bf);

    se = (se + 2) % 3;
  }
#undef STG_A
#undef STG_B
#undef STG_H1
#undef STG_H2
#undef MFMA16
#undef SBAR
#undef GLOAD

  // ---------------- fused epilogues (per-wave output: 64 rows x 64 cols)
  const int nt = n0 / 768;   // 0=Q(pool), 1=K, 2=V(transpose)
  if (nt == 1) {
#pragma unroll
    for (int nf = 0; nf < 4; ++nf) {
      const int nc = wn * 64 + nf * 16 + fr;
      const float bvs = bias[n0 + nc];
      const int gnc = n0 - 768 + nc;
#pragma unroll
      for (int mf = 0; mf < 4; ++mf) {
        const int gmr = m0 + wm * 64 + mf * 16 + hi * 4;
#pragma unroll
        for (int j = 0; j < 4; ++j)
          Kbuf[(size_t)(gmr + j) * 768 + gnc] = f2bf(acc[mf][nf][j] + bvs);
      }
    }
  } else if (nt == 0) {
#pragma unroll
    for (int mf = 0; mf < 4; ++mf) {
      const int sl = s0 + wm * 64 + mf * 16 + hi * 4;   // seq of j=0
      const float4 km = *(const float4*)&kbias[b * SS + sl];
      const float2 iv = *(const float2*)&invn[b * OL + (sl >> 1)];
      const float w0 = (km.x == 0.f) ? iv.x : 0.f;
      const float w1 = (km.y == 0.f) ? iv.x : 0.f;
      const float w2 = (km.z == 0.f) ? iv.y : 0.f;
      const float w3 = (km.w == 0.f) ? iv.y : 0.f;
      const int o0 = b * OL + (sl >> 1);
#pragma unroll
      for (int nf = 0; nf < 4; ++nf) {
        const int gnc = n0 + wn * 64 + nf * 16 + fr;
        const float bvs = bias[gnc];
        const f32x4 a = acc[mf][nf];
        qp[(size_t)o0 * DD + gnc] = f2bf((a[0] + bvs) * w0 + (a[1] + bvs) * w1);
        qp[(size_t)(o0 + 1) * DD + gnc] = f2bf((a[2] + bvs) * w2 + (a[3] + bvs) * w3);
      }
    }
  } else {
    // V: bias + bf16 into LDS [256 n][136 m] (slots 0-1, retired above),
    // then transposed coalesced store. 69632 B < 98304 (slot 2 untouched).
    unsigned short* lt = (unsigned short*)smem;
#pragma unroll
    for (int nf = 0; nf < 4; ++nf) {
      const int nl = wn * 64 + nf * 16 + fr;
      const float bvs = bias[n0 + nl];
#pragma unroll
      for (int mf = 0; mf < 4; ++mf) {
        const int ml = wm * 64 + mf * 16 + hi * 4;
        ushort4 pk;
        pk.x = f2bf(acc[mf][nf][0] + bvs);
        pk.y = f2bf(acc[mf][nf][1] + bvs);
        pk.z = f2bf(acc[mf][nf][2] + bvs);
        pk.w = f2bf(acc[mf][nf][3] + bvs);
        *(ushort4*)&lt[nl * 136 + ml] = pk;
      }
    }
    __syncthreads();
#pragma unroll
    for (int i = 0; i < 8; ++i) {
      const int task = i * 512 + t;
      const int r = task >> 4;           // n-local 0..255
      const int ch = task & 15;          // 8-elem chunk of m (0..15)
      const u16x8 v = *(const u16x8*)&lt[r * 136 + ch * 8];
      const int nv = n0 - 1536 + r;
      const int h2 = nv >> 6, d2 = nv & 63;
      *(u16x8*)(vT + ((size_t)((b * HH + h2) * HDIM + d2)) * 512 + s0 + ch * 8) = v;
    }
  }
}

// ---------------------------------------------------------------- attention
// slopes pre-scaled by log2(e)
__constant__ float c_slopes2[12] = {
    0.72134752f, 0.36067376f, 0.18033688f, 0.09016844f,
    0.04508422f, 0.02254211f, 0.011271055f, 0.0056355275f,
    1.02013945f, 0.51006972f, 0.25503486f, 0.12751743f};

// 4-wave block; block covers HALF the q-rows of one (b,h): wave w owns
// 32 q-rows (2 m-frags). 768 blocks x 4 waves = 3072 waves = 3/SIMD.
__global__ __launch_bounds__(256) void attn_mfma(
    const unsigned short* __restrict__ qp,    // [B][OL][768] bf16
    const unsigned short* __restrict__ Kb,    // [B*S][768] bf16
    const unsigned short* __restrict__ vT,    // [B][H][64][512] bf16
    const float* __restrict__ kbias,          // [B][S], pre-scaled log2e
    const unsigned char* __restrict__ nmask,  // [B][OL]
    float* __restrict__ out) {                // [B][OL][768]
  __shared__ __align__(16) char smem[51200];
  const int t = threadIdx.x;
  const int lane = t & 63;
  const int w = t >> 6;
  const int wq = __builtin_amdgcn_readfirstlane(w);
  const int fr = lane & 15, hi = lane >> 4;

  const int p = blockIdx.x;
  const int l = (p & 7) * 96 + (p >> 3);
  const int qb = l & 1;
  const int bh = l >> 1;
  const int h = bh % HH, b = bh / HH;
  const int q0 = qb * 128 + wq * 32;

  char* ptb = smem + 32768 + wq * 4096;
  float* kbl = (float*)(smem + 49152);

  const int srow = lane >> 3;
  const int scol = ((lane & 7) ^ srow) * 8;

#define GLOAD(SRC, DST)                                                        \
  __builtin_amdgcn_global_load_lds(                                           \
      (const __attribute__((address_space(1))) unsigned int*)(SRC),           \
      (__attribute__((address_space(3))) unsigned int*)(DST), 16, 0, 0)

  if (wq == 0) {
    GLOAD(kbias + b * SS + lane * 4, smem + 49152);
    GLOAD(kbias + b * SS + 256 + lane * 4, smem + 50176);
  }

  bf16x8 qf[2][2];
#pragma unroll
  for (int m = 0; m < 2; ++m)
#pragma unroll
    for (int ks = 0; ks < 2; ++ks)
      qf[m][ks] = *(const bf16x8*)(qp + (size_t)(b * OL + q0 + m * 16 + fr) * DD +
                                   h * HDIM + ks * 32 + hi * 8);

  int nmv = (int)nmask[b * OL + q0 + (lane & 31)];
  int qmbits = 0;
#pragma unroll
  for (int m = 0; m < 2; ++m)
#pragma unroll
    for (int j = 0; j < 4; ++j)
      if (__shfl(nmv, m * 16 + hi * 4 + j, 64)) qmbits |= 1 << (m * 4 + j);

  const float slope2 = c_slopes2[h];
  f32x4 oacc[2][4] = {};
  float lpart[2][4] = {};

#define STAGE(TILE, BUF) do {                                                  \
    char* kd_ = smem + (BUF) * 8192 + wq * 2048;                               \
    char* vd_ = smem + 16384 + (BUF) * 8192 + wq * 2048;                       \
    const unsigned short* ks_ =                                                \
        Kb + (size_t)(b * SS + (TILE) * 64 + wq * 16 + srow) * 768 + h * HDIM + scol; \
    const unsigned short* vs_ =                                                \
        vT + (size_t)((b * HH + h) * HDIM + wq * 16 + srow) * SS + (TILE) * 64 + scol; \
    GLOAD(ks_, kd_);                                                           \
    GLOAD(ks_ + (size_t)8 * 768, kd_ + 1024);                                  \
    GLOAD(vs_, vd_);                                                           \
    GLOAD(vs_ + (size_t)8 * SS, vd_ + 1024);                                   \
  } while (0)

  __builtin_amdgcn_sched_barrier(0);
  STAGE(0, 0);
  STAGE(1, 1);
  __builtin_amdgcn_sched_barrier(0);

  for (int tile = 0; tile < 8; ++tile) {
    const int cur = tile & 1;
    const int key0 = tile * 64;
    if (tile < 7) {
      asm volatile("s_waitcnt vmcnt(4)" ::: "memory");
    } else {
      asm volatile("s_waitcnt vmcnt(0)" ::: "memory");
    }
    __builtin_amdgcn_sched_barrier(0);
    __builtin_amdgcn_s_barrier();
    __builtin_amdgcn_sched_barrier(0);

    char* ktb = smem + cur * 8192;
    char* vtb = smem + 16384 + cur * 8192;

    // ---- QK^T
    f32x4 sacc[2][4] = {};
#pragma unroll
    for (int ks = 0; ks < 2; ++ks) {
      bf16x8 kf[4];
#pragma unroll
      for (int n = 0; n < 4; ++n) {
        const int by = ((n * 16 + fr) * 128 + (ks * 64 + hi * 16)) ^ ((fr & 7) << 4);
        kf[n] = *(const bf16x8*)(ktb + by);
      }
#pragma unroll
      for (int m = 0; m < 2; ++m)
#pragma unroll
        for (int n = 0; n < 4; ++n)
          sacc[m][n] = __builtin_amdgcn_mfma_f32_16x16x32_bf16(qf[m][ks], kf[n], sacc[m][n], 0, 0, 0);
    }

    // ---- fixed-max log2-domain softmax; P -> LDS (bf16)
    float kbv[4], keyfv[4];
#pragma unroll
    for (int n = 0; n < 4; ++n) {
      kbv[n] = kbl[key0 + n * 16 + fr];
      keyfv[n] = (float)(key0 + n * 16 + fr);
    }
#pragma unroll
    for (int m = 0; m < 2; ++m) {
#pragma unroll
      for (int j = 0; j < 4; ++j) {
        const bool qm = (qmbits >> (m * 4 + j)) & 1;
        const float qvf = (float)(q0 + m * 16 + hi * 4 + j);
        float lp = lpart[m][j];
#pragma unroll
        for (int n = 0; n < 4; ++n) {
          const float biasv = qm ? kbv[n] : 0.f;
          const float rel = fabsf(keyfv[n] - qvf);
          float tv = fmaf(sacc[m][n][j], 0.18033688011f, biasv);
          tv = fmaf(rel, -slope2, tv);
          float pe;
          asm("v_exp_f32 %0, %1" : "=v"(pe) : "v"(tv));
          lp += pe;
          const int by = ((m * 16 + hi * 4 + j) * 128 + (n * 16 + fr) * 2) ^
                         (((hi * 4 + j) & 7) << 4);
          *(unsigned short*)(ptb + by) = f2bf(pe);
        }
        lpart[m][j] = lp;
      }
    }
    asm volatile("s_waitcnt lgkmcnt(0)" ::: "memory");
    __builtin_amdgcn_sched_barrier(0);

    // ---- PV
#pragma unroll
    for (int ks = 0; ks < 2; ++ks) {
      bf16x8 pf[2], vf[4];
#pragma unroll
      for (int m = 0; m < 2; ++m) {
        const int by = ((m * 16 + fr) * 128 + (ks * 64 + hi * 16)) ^ ((fr & 7) << 4);
        pf[m] = *(const bf16x8*)(ptb + by);
      }
#pragma unroll
      for (int nd = 0; nd < 4; ++nd) {
        const int by = ((nd * 16 + fr) * 128 + (ks * 64 + hi * 16)) ^ ((fr & 7) << 4);
        vf[nd] = *(const bf16x8*)(vtb + by);
      }
#pragma unroll
      for (int m = 0; m < 2; ++m)
#pragma unroll
        for (int nd = 0; nd < 4; ++nd)
          oacc[m][nd] = __builtin_amdgcn_mfma_f32_16x16x32_bf16(pf[m], vf[nd], oacc[m][nd], 0, 0, 0);
    }

    __builtin_amdgcn_sched_barrier(0);
    __builtin_amdgcn_s_barrier();
    __builtin_amdgcn_sched_barrier(0);
    if (tile + 2 < 8) STAGE(tile + 2, cur);
  }
#undef STAGE
#undef GLOAD

  // ---- epilogue
  float* ot = (float*)(smem + wq * 8704);   // 32 x 68 f32
#pragma unroll
  for (int m = 0; m < 2; ++m)
#pragma unroll
    for (int j = 0; j < 4; ++j) {
      float lv = lpart[m][j];
      lv += __shfl_xor(lv, 1, 64);
      lv += __shfl_xor(lv, 2, 64);
      lv += __shfl_xor(lv, 4, 64);
      lv += __shfl_xor(lv, 8, 64);
      const float rl = 1.f / lv;
      const int row = m * 16 + hi * 4 + j;
#pragma unroll
      for (int nd = 0; nd < 4; ++nd)
        ot[row * 68 + nd * 16 + fr] = oacc[m][nd][j] * rl;
    }
  asm volatile("s_waitcnt lgkmcnt(0)" ::: "memory");
  __builtin_amdgcn_sched_barrier(0);
#pragma unroll
  for (int i = 0; i < 8; ++i) {
    const int idx = i * 64 + lane;
    const int row = idx >> 4, c4 = idx & 15;
    const float4 v = *(const float4*)&ot[row * 68 + c4 * 4];
    *(float4*)(out + (size_t)(b * OL + q0 + row) * DD + h * HDIM + c4 * 4) = v;
  }
}

// ---------------------------------------------------------------- launch
extern "C" void kernel_launch(void* const* d_in, const int* in_sizes, int n_in,
                              void* d_out, int out_size, void* d_ws, size_t ws_size,
                              hipStream_t stream) {
  const float* hidden = (const float*)d_in[0];
  const void* maskraw = d_in[1];
  const float* W = (const float*)d_in[2];
  const float* bias = (const float*)d_in[3];
  float* out = (float*)d_out;

  char* ws = (char*)d_ws;
  unsigned short* Abf  = (unsigned short*)(ws);                 // 25,165,824 B
  unsigned short* Btb  = (unsigned short*)(ws + 25165824);      //  3,538,944 B
  unsigned short* Kbuf = (unsigned short*)(ws + 28704768);      // 25,165,824 B
  unsigned short* vT   = (unsigned short*)(ws + 53870592);      // 25,165,824 B
  unsigned short* qp   = (unsigned short*)(ws + 79036416);      // 12,582,912 B
  float* kbias         = (float*)(ws + 91619328);               //     65,536 B
  float* invn          = (float*)(ws + 91684864);               //     32,768 B
  unsigned char* nmask = (unsigned char*)(ws + 91717632);       //      8,192 B

  float* out_nm = out + (size_t)BB * OL * DD;  // new_mask part of d_out

  conv_f32_bf16<<<(GM * DD / 4 + 255) / 256, 256, 0, stream>>>(hidden, Abf, GM * DD / 4);
  conv_f32_bf16<<<(NQKV * DD / 4 + 255) / 256, 256, 0, stream>>>(W, Btb, NQKV * DD / 4);
  prep_mask<<<BB, SS, 0, stream>>>(maskraw, kbias, invn, nmask, out_nm);
  gemm_qkv<<<1152, 512, 0, stream>>>(Abf, Btb, bias, Kbuf, qp, vT, kbias, invn);
  attn_mfma<<<768, 256, 0, stream>>>(qp, Kbuf, vT, kbias, nmask, out);
}

// Round 10
// 112.863 us; speedup vs baseline: 1.0174x; 1.0174x over previous
//
#include <hip/hip_runtime.h>

// Problem constants
#define BB 32
#define SS 512
#define DD 768
#define HH 12
#define HDIM 64
#define OL 256        // pooled query length
#define NQKV 2304     // 3*DD
#define GM (BB*SS)    // 16384 rows into the QKV GEMM

#define NEG2 (-14426.9504089f)   // -10000 * log2(e)

typedef __bf16 bf16_t;
typedef bf16_t bf16x8 __attribute__((ext_vector_type(8)));
typedef float f32x4 __attribute__((ext_vector_type(4)));
typedef unsigned short u16x8 __attribute__((ext_vector_type(8)));

__device__ __forceinline__ unsigned short f2bf(float f) {
  unsigned u = __float_as_uint(f);
  u = u + 0x7FFFu + ((u >> 16) & 1u);   // RNE
  return (unsigned short)(u >> 16);
}
__device__ __forceinline__ float b2f(unsigned short s) {
  return __uint_as_float(((unsigned)s) << 16);
}

// ---------------------------------------------------------------- conversions
__global__ void conv_f32_bf16(const float* __restrict__ in,
                              unsigned short* __restrict__ out, int n4) {
  int i = blockIdx.x * blockDim.x + threadIdx.x;
  if (i >= n4) return;
  float4 v = ((const float4*)in)[i];
  ushort4 o;
  o.x = f2bf(v.x); o.y = f2bf(v.y); o.z = f2bf(v.z); o.w = f2bf(v.w);
  ((ushort4*)out)[i] = o;
}

// ---------------------------------------------------------------- mask prep
// kbias pre-scaled by log2(e): 0 valid, -14427 masked.
__global__ void prep_mask(const void* __restrict__ mraw,
                          float* __restrict__ kbias,
                          float* __restrict__ invn,
                          unsigned char* __restrict__ nmask,
                          float* __restrict__ out_nm) {
  int b = blockIdx.x, t = threadIdx.x;
  const unsigned char* mb = (const unsigned char*)mraw;
  bool isbyte = (mb[1] != 0);
  int idx = b * SS + t;
  int mv = isbyte ? (int)(mb[idx] != 0) : (int)(((const int*)mraw)[idx] != 0);
  kbias[idx] = mv ? 0.f : NEG2;
  if (t < OL) {
    int i0 = b * SS + 2 * t, i1 = i0 + 1;
    int m0 = isbyte ? (int)(mb[i0] != 0) : (int)(((const int*)mraw)[i0] != 0);
    int m1 = isbyte ? (int)(mb[i1] != 0) : (int)(((const int*)mraw)[i1] != 0);
    int n = m0 + m1;
    invn[b * OL + t] = (n > 0) ? 1.f / (float)n : 1.f;
    nmask[b * OL + t] = (n > 0) ? 1 : 0;
    out_nm[b * OL + t] = (n > 0) ? 1.f : 0.f;   // second tuple output
  }
}

// ---------------------------------------------------------------- QKV GEMM
// 128x256 tile, BK=64, 8 waves (2M x 4N, per-wave 64x64), RING-3 LDS
// (3 x 48 KiB). m201-style phases: reads+stage ISSUE BEFORE the barrier
// (barrier-wait absorbs LDS latency), lgkm wait after, 16 MFMA per phase.
// vmcnt(6) steady (before ph2/ph4 barriers), never drains mid-loop.
// Fused epilogues: n-tiles 0-2 -> pooled qp; 3-5 -> Kbuf; 6-8 -> vT.
__global__ __launch_bounds__(512, 1) void gemm_qkv(
    const unsigned short* __restrict__ A,
    const unsigned short* __restrict__ Bt,
    const float* __restrict__ bias,
    unsigned short* __restrict__ Kbuf,   // [B*S][768]
    unsigned short* __restrict__ qp,     // [B*OL][768]
    unsigned short* __restrict__ vT,     // [B][H][64][512]
    const float* __restrict__ kbias,
    const float* __restrict__ invn) {
  __shared__ __align__(16) char smem[147456];   // 3 slots x (A 16K + B 32K)

  const int t = threadIdx.x;
  const int lane = t & 63;
  const int w = t >> 6;          // 0..7
  const int wm = w >> 2;         // 0..1
  const int wn = w & 3;          // 0..3
  const int fr = lane & 15, hi = lane >> 4;

  // T1: 1152 blocks = 8 XCDs x 144 (n fastest: A panel L2-resident per XCD)
  const int p = blockIdx.x;
  const int l = (p & 7) * 144 + (p >> 3);
  const int m0 = (l / 9) * 128;
  const int n0 = (l % 9) * 256;
  const int b = m0 >> 9;
  const int s0 = m0 & 511;

  f32x4 acc[4][4] = {};

  const int sr8 = lane >> 3;
  const int sx8 = ((lane & 7) ^ sr8) * 8;       // pre-swizzled source col
  const int wq = __builtin_amdgcn_readfirstlane(w);
  const unsigned short* aS = A + (size_t)(m0 + wq * 16 + sr8) * DD + sx8;
  const unsigned short* bS = Bt + (size_t)(n0 + wq * 32 + sr8) * DD + sx8;

#define GLOAD(SRC, DST)                                                        \
  __builtin_amdgcn_global_load_lds(                                           \
      (const __attribute__((address_space(1))) unsigned int*)(SRC),           \
      (__attribute__((address_space(3))) unsigned int*)(DST), 16, 0, 0)

  // per K-tile staging: A = 2 issues/thread, B = 4 issues/thread
#define STG_A(KT, SB, Q) GLOAD(aS + (size_t)(8 * (Q)) * DD + (KT) * 64,        \
                               (SB) + (wq * 16 + 8 * (Q)) * 128)
#define STG_B(KT, SB, Q) GLOAD(bS + (size_t)(8 * (Q)) * DD + (KT) * 64,        \
                               (SB) + 16384 + (wq * 32 + 8 * (Q)) * 128)
#define STG_H1(KT, SB) do { STG_A(KT, SB, 0); STG_A(KT, SB, 1); STG_B(KT, SB, 0); } while (0)
#define STG_H2(KT, SB) do { STG_B(KT, SB, 1); STG_B(KT, SB, 2); STG_B(KT, SB, 3); } while (0)

#define RD(SB, CB)                                                             \
  do {                                                                         \
    _Pragma("unroll")                                                          \
    for (int f_ = 0; f_ < 4; ++f_)                                             \
      af[f_] = *(const bf16x8*)((SB) + arow + f_ * 2048 + (CB));               \
    _Pragma("unroll")                                                          \
    for (int f_ = 0; f_ < 4; ++f_)                                             \
      bf[f_] = *(const bf16x8*)((SB) + brow + f_ * 2048 + (CB));               \
  } while (0)

  // barrier AFTER issues: barrier-wait hides LDS/stage latency
#define PHASE_SYNC()                                                           \
  do {                                                                         \
    __builtin_amdgcn_sched_barrier(0);                                         \
    __builtin_amdgcn_s_barrier();                                              \
    __builtin_amdgcn_sched_barrier(0);                                         \
  } while (0)

#define MFMA16()                                                               \
  do {                                                                         \
    __builtin_amdgcn_s_setprio(1);                                             \
    _Pragma("unroll")                                                          \
    for (int mf_ = 0; mf_ < 4; ++mf_)                                          \
      _Pragma("unroll")                                                        \
      for (int nf_ = 0; nf_ < 4; ++nf_)                                        \
        acc[mf_][nf_] = __builtin_amdgcn_mfma_f32_16x16x32_bf16(               \
            af[mf_], bf[nf_], acc[mf_][nf_], 0, 0, 0);                         \
    __builtin_amdgcn_s_setprio(0);                                             \
  } while (0)

  const int cb0 = (hi * 16) ^ ((fr & 7) << 4);
  const int cb1 = (64 + hi * 16) ^ ((fr & 7) << 4);
  const int arow = (wm * 64 + fr) * 128;          // + mf*2048
  const int brow = 16384 + (wn * 64 + fr) * 128;  // + nf*2048

  // prologue: tiles 0 -> slot0, 1 -> slot1 (12 loads/thread outstanding);
  // vmcnt(6): tile 0 landed; barrier publishes it to all waves.
  STG_H1(0, smem); STG_H2(0, smem);
  STG_H1(1, smem + 49152); STG_H2(1, smem + 49152);
  asm volatile("s_waitcnt vmcnt(6)" ::: "memory");
  PHASE_SYNC();

  int se = 0;
#pragma unroll
  for (int it = 0; it < 6; ++it) {
    char* sE = smem + se * 49152;
    char* sO = smem + (se == 2 ? 0 : se + 1) * 49152;
    char* dE = smem + (se == 0 ? 2 : se - 1) * 49152;
    char* dO = sE;
    const int ke = 2 * it + 2, ko = 2 * it + 3;

    bf16x8 af[4], bf[4];

    // ---- ph1: even K-tile, ks=0  (sE valid since previous ph4 barrier)
    RD(sE, cb0);
    if (it < 5) STG_H1(ke, dE);
    PHASE_SYNC();
    MFMA16();

    // ---- ph2: even K-tile, ks=1; vmcnt publishes odd tile before barrier
    RD(sE, cb1);
    if (it < 5) {
      STG_H2(ke, dE);
      asm volatile("s_waitcnt vmcnt(6)" ::: "memory");
    } else {
      asm volatile("s_waitcnt vmcnt(0)" ::: "memory");
    }
    PHASE_SYNC();
    MFMA16();

    // ---- ph3: odd K-tile, ks=0
    RD(sO, cb0);
    if (it < 5) STG_H1(ko, dO);
    PHASE_SYNC();
    MFMA16();

    // ---- ph4: odd K-tile, ks=1; vmcnt publishes next even tile
    RD(sO, cb1);
    if (it < 5) {
      STG_H2(ko, dO);
      asm volatile("s_waitcnt vmcnt(6)" ::: "memory");
    }
    PHASE_SYNC();
    MFMA16();

    se = (se + 2) % 3;
  }
#undef STG_A
#undef STG_B
#undef STG_H1
#undef STG_H2
#undef RD
#undef MFMA16
#undef PHASE_SYNC
#undef GLOAD

  // ---------------- fused epilogues (per-wave output: 64 rows x 64 cols)
  const int nt = n0 / 768;   // 0=Q(pool), 1=K, 2=V(transpose)
  if (nt == 1) {
#pragma unroll
    for (int nf = 0; nf < 4; ++nf) {
      const int nc = wn * 64 + nf * 16 + fr;
      const float bvs = bias[n0 + nc];
      const int gnc = n0 - 768 + nc;
#pragma unroll
      for (int mf = 0; mf < 4; ++mf) {
        const int gmr = m0 + wm * 64 + mf * 16 + hi * 4;
#pragma unroll
        for (int j = 0; j < 4; ++j)
          Kbuf[(size_t)(gmr + j) * 768 + gnc] = f2bf(acc[mf][nf][j] + bvs);
      }
    }
  } else if (nt == 0) {
#pragma unroll
    for (int mf = 0; mf < 4; ++mf) {
      const int sl = s0 + wm * 64 + mf * 16 + hi * 4;   // seq of j=0
      const float4 km = *(const float4*)&kbias[b * SS + sl];
      const float2 iv = *(const float2*)&invn[b * OL + (sl >> 1)];
      const float w0 = (km.x == 0.f) ? iv.x : 0.f;
      const float w1 = (km.y == 0.f) ? iv.x : 0.f;
      const float w2 = (km.z == 0.f) ? iv.y : 0.f;
      const float w3 = (km.w == 0.f) ? iv.y : 0.f;
      const int o0 = b * OL + (sl >> 1);
#pragma unroll
      for (int nf = 0; nf < 4; ++nf) {
        const int gnc = n0 + wn * 64 + nf * 16 + fr;
        const float bvs = bias[gnc];
        const f32x4 a = acc[mf][nf];
        qp[(size_t)o0 * DD + gnc] = f2bf((a[0] + bvs) * w0 + (a[1] + bvs) * w1);
        qp[(size_t)(o0 + 1) * DD + gnc] = f2bf((a[2] + bvs) * w2 + (a[3] + bvs) * w3);
      }
    }
  } else {
    // V: bias + bf16 into LDS [256 n][136 m] (slots 0-1, retired above),
    // then transposed coalesced store. 69632 B < 98304 (slot 2 untouched).
    unsigned short* lt = (unsigned short*)smem;
#pragma unroll
    for (int nf = 0; nf < 4; ++nf) {
      const int nl = wn * 64 + nf * 16 + fr;
      const float bvs = bias[n0 + nl];
#pragma unroll
      for (int mf = 0; mf < 4; ++mf) {
        const int ml = wm * 64 + mf * 16 + hi * 4;
        ushort4 pk;
        pk.x = f2bf(acc[mf][nf][0] + bvs);
        pk.y = f2bf(acc[mf][nf][1] + bvs);
        pk.z = f2bf(acc[mf][nf][2] + bvs);
        pk.w = f2bf(acc[mf][nf][3] + bvs);
        *(ushort4*)&lt[nl * 136 + ml] = pk;
      }
    }
    __syncthreads();
#pragma unroll
    for (int i = 0; i < 8; ++i) {
      const int task = i * 512 + t;
      const int r = task >> 4;           // n-local 0..255
      const int ch = task & 15;          // 8-elem chunk of m (0..15)
      const u16x8 v = *(const u16x8*)&lt[r * 136 + ch * 8];
      const int nv = n0 - 1536 + r;
      const int h2 = nv >> 6, d2 = nv & 63;
      *(u16x8*)(vT + ((size_t)((b * HH + h2) * HDIM + d2)) * 512 + s0 + ch * 8) = v;
    }
  }
}

// ---------------------------------------------------------------- attention
// slopes pre-scaled by log2(e)
__constant__ float c_slopes2[12] = {
    0.72134752f, 0.36067376f, 0.18033688f, 0.09016844f,
    0.04508422f, 0.02254211f, 0.011271055f, 0.0056355275f,
    1.02013945f, 0.51006972f, 0.25503486f, 0.12751743f};

// 4-wave block; block covers HALF the q-rows of one (b,h): wave w owns
// 32 q-rows (2 m-frags). 768 blocks x 4 waves = 3072 waves = 3/SIMD.
__global__ __launch_bounds__(256) void attn_mfma(
    const unsigned short* __restrict__ qp,    // [B][OL][768] bf16
    const unsigned short* __restrict__ Kb,    // [B*S][768] bf16
    const unsigned short* __restrict__ vT,    // [B][H][64][512] bf16
    const float* __restrict__ kbias,          // [B][S], pre-scaled log2e
    const unsigned char* __restrict__ nmask,  // [B][OL]
    float* __restrict__ out) {                // [B][OL][768]
  __shared__ __align__(16) char smem[51200];
  const int t = threadIdx.x;
  const int lane = t & 63;
  const int w = t >> 6;
  const int wq = __builtin_amdgcn_readfirstlane(w);
  const int fr = lane & 15, hi = lane >> 4;

  const int p = blockIdx.x;
  const int l = (p & 7) * 96 + (p >> 3);
  const int qb = l & 1;
  const int bh = l >> 1;
  const int h = bh % HH, b = bh / HH;
  const int q0 = qb * 128 + wq * 32;

  char* ptb = smem + 32768 + wq * 4096;
  float* kbl = (float*)(smem + 49152);

  const int srow = lane >> 3;
  const int scol = ((lane & 7) ^ srow) * 8;

#define GLOAD(SRC, DST)                                                        \
  __builtin_amdgcn_global_load_lds(                                           \
      (const __attribute__((address_space(1))) unsigned int*)(SRC),           \
      (__attribute__((address_space(3))) unsigned int*)(DST), 16, 0, 0)

  if (wq == 0) {
    GLOAD(kbias + b * SS + lane * 4, smem + 49152);
    GLOAD(kbias + b * SS + 256 + lane * 4, smem + 50176);
  }

  bf16x8 qf[2][2];
#pragma unroll
  for (int m = 0; m < 2; ++m)
#pragma unroll
    for (int ks = 0; ks < 2; ++ks)
      qf[m][ks] = *(const bf16x8*)(qp + (size_t)(b * OL + q0 + m * 16 + fr) * DD +
                                   h * HDIM + ks * 32 + hi * 8);

  int nmv = (int)nmask[b * OL + q0 + (lane & 31)];
  int qmbits = 0;
#pragma unroll
  for (int m = 0; m < 2; ++m)
#pragma unroll
    for (int j = 0; j < 4; ++j)
      if (__shfl(nmv, m * 16 + hi * 4 + j, 64)) qmbits |= 1 << (m * 4 + j);

  const float slope2 = c_slopes2[h];
  f32x4 oacc[2][4] = {};
  float lpart[2][4] = {};

#define STAGE(TILE, BUF) do {                                                  \
    char* kd_ = smem + (BUF) * 8192 + wq * 2048;                               \
    char* vd_ = smem + 16384 + (BUF) * 8192 + wq * 2048;                       \
    const unsigned short* ks_ =                                                \
        Kb + (size_t)(b * SS + (TILE) * 64 + wq * 16 + srow) * 768 + h * HDIM + scol; \
    const unsigned short* vs_ =                                                \
        vT + (size_t)((b * HH + h) * HDIM + wq * 16 + srow) * SS + (TILE) * 64 + scol; \
    GLOAD(ks_, kd_);                                                           \
    GLOAD(ks_ + (size_t)8 * 768, kd_ + 1024);                                  \
    GLOAD(vs_, vd_);                                                           \
    GLOAD(vs_ + (size_t)8 * SS, vd_ + 1024);                                   \
  } while (0)

  __builtin_amdgcn_sched_barrier(0);
  STAGE(0, 0);
  STAGE(1, 1);
  __builtin_amdgcn_sched_barrier(0);

  for (int tile = 0; tile < 8; ++tile) {
    const int cur = tile & 1;
    const int key0 = tile * 64;
    if (tile < 7) {
      asm volatile("s_waitcnt vmcnt(4)" ::: "memory");
    } else {
      asm volatile("s_waitcnt vmcnt(0)" ::: "memory");
    }
    __builtin_amdgcn_sched_barrier(0);
    __builtin_amdgcn_s_barrier();
    __builtin_amdgcn_sched_barrier(0);

    char* ktb = smem + cur * 8192;
    char* vtb = smem + 16384 + cur * 8192;

    // ---- QK^T
    f32x4 sacc[2][4] = {};
#pragma unroll
    for (int ks = 0; ks < 2; ++ks) {
      bf16x8 kf[4];
#pragma unroll
      for (int n = 0; n < 4; ++n) {
        const int by = ((n * 16 + fr) * 128 + (ks * 64 + hi * 16)) ^ ((fr & 7) << 4);
        kf[n] = *(const bf16x8*)(ktb + by);
      }
#pragma unroll
      for (int m = 0; m < 2; ++m)
#pragma unroll
        for (int n = 0; n < 4; ++n)
          sacc[m][n] = __builtin_amdgcn_mfma_f32_16x16x32_bf16(qf[m][ks], kf[n], sacc[m][n], 0, 0, 0);
    }

    // ---- fixed-max log2-domain softmax; P -> LDS (bf16)
    float kbv[4], keyfv[4];
#pragma unroll
    for (int n = 0; n < 4; ++n) {
      kbv[n] = kbl[key0 + n * 16 + fr];
      keyfv[n] = (float)(key0 + n * 16 + fr);
    }
#pragma unroll
    for (int m = 0; m < 2; ++m) {
#pragma unroll
      for (int j = 0; j < 4; ++j) {
        const bool qm = (qmbits >> (m * 4 + j)) & 1;
        const float qvf = (float)(q0 + m * 16 + hi * 4 + j);
        float lp = lpart[m][j];
#pragma unroll
        for (int n = 0; n < 4; ++n) {
          const float biasv = qm ? kbv[n] : 0.f;
          const float rel = fabsf(keyfv[n] - qvf);
          float tv = fmaf(sacc[m][n][j], 0.18033688011f, biasv);
          tv = fmaf(rel, -slope2, tv);
          float pe;
          asm("v_exp_f32 %0, %1" : "=v"(pe) : "v"(tv));
          lp += pe;
          const int by = ((m * 16 + hi * 4 + j) * 128 + (n * 16 + fr) * 2) ^
                         (((hi * 4 + j) & 7) << 4);
          *(unsigned short*)(ptb + by) = f2bf(pe);
        }
        lpart[m][j] = lp;
      }
    }
    asm volatile("s_waitcnt lgkmcnt(0)" ::: "memory");
    __builtin_amdgcn_sched_barrier(0);

    // ---- PV
#pragma unroll
    for (int ks = 0; ks < 2; ++ks) {
      bf16x8 pf[2], vf[4];
#pragma unroll
      for (int m = 0; m < 2; ++m) {
        const int by = ((m * 16 + fr) * 128 + (ks * 64 + hi * 16)) ^ ((fr & 7) << 4);
        pf[m] = *(const bf16x8*)(ptb + by);
      }
#pragma unroll
      for (int nd = 0; nd < 4; ++nd) {
        const int by = ((nd * 16 + fr) * 128 + (ks * 64 + hi * 16)) ^ ((fr & 7) << 4);
        vf[nd] = *(const bf16x8*)(vtb + by);
      }
#pragma unroll
      for (int m = 0; m < 2; ++m)
#pragma unroll
        for (int nd = 0; nd < 4; ++nd)
          oacc[m][nd] = __builtin_amdgcn_mfma_f32_16x16x32_bf16(pf[m], vf[nd], oacc[m][nd], 0, 0, 0);
    }

    __builtin_amdgcn_sched_barrier(0);
    __builtin_amdgcn_s_barrier();
    __builtin_amdgcn_sched_barrier(0);
    if (tile + 2 < 8) STAGE(tile + 2, cur);
  }
#undef STAGE
#undef GLOAD

  // ---- epilogue
  float* ot = (float*)(smem + wq * 8704);   // 32 x 68 f32
#pragma unroll
  for (int m = 0; m < 2; ++m)
#pragma unroll
    for (int j = 0; j < 4; ++j) {
      float lv = lpart[m][j];
      lv += __shfl_xor(lv, 1, 64);
      lv += __shfl_xor(lv, 2, 64);
      lv += __shfl_xor(lv, 4, 64);
      lv += __shfl_xor(lv, 8, 64);
      const float rl = 1.f / lv;
      const int row = m * 16 + hi * 4 + j;
#pragma unroll
      for (int nd = 0; nd < 4; ++nd)
        ot[row * 68 + nd * 16 + fr] = oacc[m][nd][j] * rl;
    }
  asm volatile("s_waitcnt lgkmcnt(0)" ::: "memory");
  __builtin_amdgcn_sched_barrier(0);
#pragma unroll
  for (int i = 0; i < 8; ++i) {
    const int idx = i * 64 + lane;
    const int row = idx >> 4, c4 = idx & 15;
    const float4 v = *(const float4*)&ot[row * 68 + c4 * 4];
    *(float4*)(out + (size_t)(b * OL + q0 + row) * DD + h * HDIM + c4 * 4) = v;
  }
}

// ---------------------------------------------------------------- launch
extern "C" void kernel_launch(void* const* d_in, const int* in_sizes, int n_in,
                              void* d_out, int out_size, void* d_ws, size_t ws_size,
                              hipStream_t stream) {
  const float* hidden = (const float*)d_in[0];
  const void* maskraw = d_in[1];
  const float* W = (const float*)d_in[2];
  const float* bias = (const float*)d_in[3];
  float* out = (float*)d_out;

  char* ws = (char*)d_ws;
  unsigned short* Abf  = (unsigned short*)(ws);                 // 25,165,824 B
  unsigned short* Btb  = (unsigned short*)(ws + 25165824);      //  3,538,944 B
  unsigned short* Kbuf = (unsigned short*)(ws + 28704768);      // 25,165,824 B
  unsigned short* vT   = (unsigned short*)(ws + 53870592);      // 25,165,824 B
  unsigned short* qp   = (unsigned short*)(ws + 79036416);      // 12,582,912 B
  float* kbias         = (float*)(ws + 91619328);               //     65,536 B
  float* invn          = (float*)(ws + 91684864);               //     32,768 B
  unsigned char* nmask = (unsigned char*)(ws + 91717632);       //      8,192 B

  float* out_nm = out + (size_t)BB * OL * DD;  // new_mask part of d_out

  conv_f32_bf16<<<(GM * DD / 4 + 255) / 256, 256, 0, stream>>>(hidden, Abf, GM * DD / 4);
  conv_f32_bf16<<<(NQKV * DD / 4 + 255) / 256, 256, 0, stream>>>(W, Btb, NQKV * DD / 4);
  prep_mask<<<BB, SS, 0, stream>>>(maskraw, kbias, invn, nmask, out_nm);
  gemm_qkv<<<1152, 512, 0, stream>>>(Abf, Btb, bias, Kbuf, qp, vT, kbias, invn);
  attn_mfma<<<768, 256, 0, stream>>>(qp, Kbuf, vT, kbias, nmask, out);
}